// Round 8
// baseline (62.574 us; speedup 1.0000x reference)
//
#include <hip/hip_runtime.h>

// Problem constants (fixed by init_kwargs)
//   key:    [B=2, N=8, T_K=8, K_H=14, K_W=14, C=64]  f32
//   scores: [B=2, N=8, 1568, 1568]                   f32
//   h_emb:  [27, 64], w_emb: [27, 64], t_emb: [15, 64]
//   out:    [B, N, 1568, 1568] f32
//
// rel_h[bn, qh, k] = dot(h_emb[kh-qh+13, :], key[bn, k, :])   k = tk*196+kh*14+kw
// rel_w[bn, qw, k] = dot(w_emb[kw-qw+13, :], key[bn, k, :])
// rel_t[bn, tq, k] = dot(t_emb[tk-tq+ 7, :], key[bn, k, :])
// out[bn, (tq,qh,qw), k] = scores + rel_h + rel_w + rel_t

typedef float f4 __attribute__((ext_vector_type(4)));

#define BN_TOTAL    16
#define KLEN        1568
#define KLEN4       392
#define QLEN        1568
#define KV_TOTAL    (BN_TOTAL * KLEN)            // 25088 key vectors
#define REL_H_ELEMS (BN_TOTAL * 14 * KLEN)       // 351232
#define REL_T_ELEMS (BN_TOTAL * 8 * KLEN)        // 200704

#define EROWS  69     // 27 h + 27 w + 15 t
#define EPITCH 68     // 64 + 4 pad floats; 272B row stride (16B aligned)

// ---------------- stage 1: rel tables -------------------------------------
// 8 threads per key vector; slot s handles qi = s, s+8, ... (<36).
// 784 blocks x 256 threads.
__global__ __launch_bounds__(256) void rel_fused(const float* __restrict__ key,
                                                 const float* __restrict__ hemb,
                                                 const float* __restrict__ wemb,
                                                 const float* __restrict__ temb,
                                                 float* __restrict__ relh,
                                                 float* __restrict__ relw,
                                                 float* __restrict__ relt)
{
    __shared__ float se[EROWS * EPITCH];
    for (int idx = threadIdx.x; idx < EROWS * 64; idx += 256) {
        int row = idx >> 6, c = idx & 63;
        float v;
        if (row < 27)      v = hemb[row * 64 + c];
        else if (row < 54) v = wemb[(row - 27) * 64 + c];
        else               v = temb[(row - 54) * 64 + c];
        se[row * EPITCH + c] = v;
    }
    __syncthreads();

    int tid  = threadIdx.x;
    int s    = tid & 7;                         // q-slot
    int kv   = blockIdx.x * 32 + (tid >> 3);    // grid exact: 784 blocks
    int bn   = kv / KLEN;
    int k    = kv - bn * KLEN;
    int tk   = k / 196;
    int khw  = k - tk * 196;
    int kh   = khw / 14;
    int kw   = khw - kh * 14;

    f4 kr[16];
    const f4* kp = (const f4*)key + (size_t)kv * 16;
#pragma unroll
    for (int c = 0; c < 16; ++c) kr[c] = kp[c];

#pragma unroll
    for (int j = 0; j < 5; ++j) {
        int qi = s + 8 * j;                     // 0..39, guard <36
        if (qi < 36) {
            int row = (qi < 14) ? (kh - qi + 13)
                    : (qi < 28) ? (kw - qi + 54)
                                : (tk - qi + 89);
            float* dst = (qi < 14) ? relh + (size_t)(bn * 14 + qi) * KLEN
                       : (qi < 28) ? relw + (size_t)(bn * 14 + qi - 14) * KLEN
                                   : relt + (size_t)(bn * 8 + qi - 28) * KLEN;
            const f4* e = (const f4*)(se + row * EPITCH);
            f4 acc4 = {0.f, 0.f, 0.f, 0.f};
#pragma unroll
            for (int c = 0; c < 16; ++c) acc4 += kr[c] * e[c];
            dst[k] = acc4.x + acc4.y + acc4.z + acc4.w;
        }
    }
}

// ---------------- stage 2: broadcast-add ----------------------------------
// Block = (bn, tq, qh-half, chunk). Tile = 98 q-rows x 56 f4 columns.
// LDS rows 0..13  = rel_w[qw], 14..20 = rel_h[qh] + rel_t (folded).
// 4-deep software pipeline, 2 f4 per group per thread, NT stores.
#define CH4    56                   // f4 per chunk (896 B segments)
#define NCH    7                    // 392 / 56
#define SROWS  21                   // 14 w + 7 ht
#define STAGE4 (SROWS * CH4)        // 1176 f4 = 18816 B LDS
#define TILE4  (98 * CH4)           // 5488 f4 = 10*512 + 256 + 112

__global__ __launch_bounds__(256) void add_staged(const f4* __restrict__ scores,
                                                  const f4* __restrict__ relh,
                                                  const f4* __restrict__ relw,
                                                  const f4* __restrict__ relt,
                                                  f4* __restrict__ out)
{
    __shared__ f4 se[STAGE4];

    int tid = threadIdx.x;
    int b   = blockIdx.x;
    int ch  = b % NCH;  b /= NCH;
    int half = b & 1;   b >>= 1;
    int tq  = b & 7;    b >>= 3;
    int bn  = b;
    int cbase = ch * CH4;

    int obase = (bn * QLEN + tq * 196 + half * 98) * KLEN4 + cbase;

#define MKIDX(E, row, c, gi)                          \
    int row = (E) / CH4;                              \
    int c   = (E) - row * CH4;                        \
    int gi  = obase + row * KLEN4 + c;

// group G covers elements G*512+tid and G*512+256+tid; G==10's second half
// is guarded (only 112 threads).
#define LOADG(G, sv)                                              \
    {                                                             \
        int eA = (G) * 512 + tid;                                 \
        MKIDX(eA, rA, cA, giA)                                    \
        sv[0] = scores[giA];                                      \
        if ((G) < 10 || tid < 112) {                              \
            int eB = (G) * 512 + 256 + tid;                       \
            MKIDX(eB, rB, cB, giB)                                \
            sv[1] = scores[giB];                                  \
        }                                                         \
    }

#define PROCG(G, sv)                                              \
    {                                                             \
        int eA = (G) * 512 + tid;                                 \
        MKIDX(eA, rA, cA, giA)                                    \
        int qhA = rA / 14, qwA = rA - qhA * 14;                   \
        f4 vA = sv[0] + se[qwA * CH4 + cA]                        \
                      + se[(14 + qhA) * CH4 + cA];                \
        __builtin_nontemporal_store(vA, out + giA);               \
        if ((G) < 10 || tid < 112) {                              \
            int eB = (G) * 512 + 256 + tid;                       \
            MKIDX(eB, rB, cB, giB)                                \
            int qhB = rB / 14, qwB = rB - qhB * 14;               \
            f4 vB = sv[1] + se[qwB * CH4 + cB]                    \
                          + se[(14 + qhB) * CH4 + cB];            \
            __builtin_nontemporal_store(vB, out + giB);           \
        }                                                         \
    }

    f4 s0[2], s1[2], s2[2], s3[2];

    // issue the deep-latency score loads first (4 groups = 8 f4 in flight)
    LOADG(0, s0);
    LOADG(1, s1);
    LOADG(2, s2);
    LOADG(3, s3);

    // stage rel into LDS; fold t into the h rows
    {
        const f4* wrow = relw + (size_t)(bn * 14) * KLEN4 + cbase;
        const f4* hrow = relh + (size_t)(bn * 14 + half * 7) * KLEN4 + cbase;
        const f4* trow = relt + (size_t)(bn * 8 + tq) * KLEN4 + cbase;
        for (int e = tid; e < STAGE4; e += 256) {
            int r = e / CH4, c = e - r * CH4;
            f4 v;
            if (r < 14) v = wrow[(size_t)r * KLEN4 + c];
            else        v = hrow[(size_t)(r - 14) * KLEN4 + c] + trow[c];
            se[e] = v;
        }
    }
    __syncthreads();            // stage + first 4 load groups complete

    PROCG(0, s0);  LOADG(4, s0);
    PROCG(1, s1);  LOADG(5, s1);
    PROCG(2, s2);  LOADG(6, s2);
    PROCG(3, s3);  LOADG(7, s3);
    PROCG(4, s0);  LOADG(8, s0);
    PROCG(5, s1);  LOADG(9, s1);
    PROCG(6, s2);  LOADG(10, s2);
    PROCG(7, s3);
    PROCG(8, s0);
    PROCG(9, s1);
    PROCG(10, s2);

#undef MKIDX
#undef LOADG
#undef PROCG
}

extern "C" void kernel_launch(void* const* d_in, const int* in_sizes, int n_in,
                              void* d_out, int out_size, void* d_ws, size_t ws_size,
                              hipStream_t stream)
{
    const float* key    = (const float*)d_in[0];
    const float* scores = (const float*)d_in[1];
    const float* hemb   = (const float*)d_in[2];
    const float* wemb   = (const float*)d_in[3];
    const float* temb   = (const float*)d_in[4];
    float*       out    = (float*)d_out;

    size_t need = (size_t)(REL_H_ELEMS * 2 + REL_T_ELEMS) * sizeof(float); // ~3.45 MB
    if (ws_size < need) return;

    float* relh = (float*)d_ws;
    float* relw = relh + REL_H_ELEMS;
    float* relt = relw + REL_H_ELEMS;

    rel_fused<<<KV_TOTAL * 8 / 256, 256, 0, stream>>>(key, hemb, wemb, temb,
                                                      relh, relw, relt);

    // grid = bn(16) * tq(8) * half(2) * chunks(7) = 1792 = 7 blocks/CU exact
    add_staged<<<BN_TOTAL * 8 * 2 * NCH, 256, 0, stream>>>((const f4*)scores,
                                                           (const f4*)relh,
                                                           (const f4*)relw,
                                                           (const f4*)relt,
                                                           (f4*)out);
}